// Round 2
// baseline (98.071 us; speedup 1.0000x reference)
//
#include <hip/hip_runtime.h>
#include <math.h>

// DiagonalSSMKernel: out[d,h,l] = 2*Re( sum_n scaled_c[d,h,n] * exp(dt[h]*a[h,n]*l) )
// H=1024, N=32 poles, L=4096, 2 dirs. Output fp32 [2,1024,4096] = 33.5 MB.
//
// R2: occupancy 4 -> 8 blocks/CU (grid 2048, each block owns half of one h's
// L-range). 32 waves/CU hides the per-pole LDS+transcendental start latency
// that capped R1 at ~40us. Start state w = exp(da*l0) uses a double-split
// phase rate with FMA compensation (start l up to 2303); then geometric
// recurrence w *= z^256 per j-step (8 steps). 2.0 folded into scaled_c.

constexpr int H      = 1024;
constexpr int NP     = 32;
constexpr int L      = 4096;
constexpr int BLOCK  = 256;
constexpr int HALVES = 2;              // blocks per h
constexpr int SEG    = L / HALVES;     // 2048 l's per block
constexpr int CHUNK  = SEG / BLOCK;    // 8 l's per thread

constexpr float  TWOPI    = 6.283185307179586f;
constexpr double INV2PI_D = 0.15915494309189535;

__global__ __launch_bounds__(BLOCK, 8)
void ssm_vand_kernel(const float* __restrict__ log_dt,
                     const float* __restrict__ log_a_real,
                     const float* __restrict__ a_imag,
                     const float* __restrict__ coeffs,
                     float* __restrict__ out)
{
    const int h    = blockIdx.x >> 1;
    const int half = blockIdx.x & 1;
    const int t    = threadIdx.x;

    // pole[3n+0] = {dar, rate_hi, rate_lo, 0}   rate = frac(dai/2pi), dbl-split
    // pole[3n+1] = {Re(z^256), Im(z^256), 0, 0}
    // pole[3n+2] = {2*s0r, 2*s0i, 2*s1r, 2*s1i} scaled_c, both dirs
    __shared__ float4 pole[NP * 3];

    if (t < NP) {
        const int n = t;
        const float dtf = expf(log_dt[h]);
        const float ar  = -expf(log_a_real[h * NP + n]);
        const float ai  = a_imag[h * NP + n];
        const float dar = ar * dtf;
        const float dai = ai * dtf;

        // phase rate in revolutions, double-split for compensated products
        const double rate  = (double)ai * (double)dtf * INV2PI_D;
        const double ratef = rate - floor(rate);
        const float  rhi   = (float)ratef;
        const float  rlo   = (float)(ratef - (double)rhi);

        // z^256 (step between consecutive j's of one thread)
        const float e256 = expf(256.0f * dar);
        double r256 = 256.0 * rate;
        r256 -= floor(r256);
        float s256, c256;
        sincosf((float)r256 * TWOPI, &s256, &c256);

        // g = (exp(da) - 1) / a   (precise path, once)
        const float ed = expf(dar);
        float sd, cd;
        sincosf(dai, &sd, &cd);
        const float emr = ed * cd - 1.0f;
        const float emi = ed * sd;
        const float inv = 1.0f / (ar * ar + ai * ai);
        const float gr  = (emr * ar + emi * ai) * inv;
        const float gi  = (emi * ar - emr * ai) * inv;

        const float cr0 = coeffs[((0 * H + h) * NP + n) * 2 + 0];
        const float ci0 = coeffs[((0 * H + h) * NP + n) * 2 + 1];
        const float cr1 = coeffs[((1 * H + h) * NP + n) * 2 + 0];
        const float ci1 = coeffs[((1 * H + h) * NP + n) * 2 + 1];

        pole[n * 3 + 0] = make_float4(dar, rhi, rlo, 0.0f);
        pole[n * 3 + 1] = make_float4(e256 * c256, e256 * s256, 0.0f, 0.0f);
        pole[n * 3 + 2] = make_float4(2.0f * (cr0 * gr - ci0 * gi),
                                      2.0f * (cr0 * gi + ci0 * gr),
                                      2.0f * (cr1 * gr - ci1 * gi),
                                      2.0f * (cr1 * gi + ci1 * gr));
    }
    __syncthreads();

    float acc0[CHUNK];
    float acc1[CHUNK];
    #pragma unroll
    for (int j = 0; j < CHUNK; ++j) { acc0[j] = 0.0f; acc1[j] = 0.0f; }

    const float lf = (float)(half * SEG + t);   // start l for this thread

    #pragma unroll 1
    for (int n = 0; n < NP; ++n) {
        const float4 pa = pole[n * 3 + 0];
        const float4 pz = pole[n * 3 + 1];
        const float4 ps = pole[n * 3 + 2];

        // w = exp(da * l0): magnitude + compensated phase
        const float m = __expf(pa.x * lf);
        const float p = pa.y * lf;
        const float e = fmaf(pa.y, lf, -p);            // exact product residual
        float rev = (p - floorf(p)) + fmaf(pa.z, lf, e);
        float s, c;
        __sincosf(rev * TWOPI, &s, &c);
        float wr = m * c;
        float wi = m * s;

        #pragma unroll
        for (int j = 0; j < CHUNK; ++j) {
            acc0[j] = fmaf(ps.x, wr, fmaf(-ps.y, wi, acc0[j]));
            acc1[j] = fmaf(ps.z, wr, fmaf(-ps.w, wi, acc1[j]));
            const float nwr = fmaf(wr, pz.x, -(wi * pz.y));
            wi              = fmaf(wi, pz.x,  (wr * pz.y));
            wr = nwr;
        }
    }

    float* o0 = out + (size_t)h * L + half * SEG + t;   // dir 0
    float* o1 = o0 + (size_t)H * L;                     // dir 1
    #pragma unroll
    for (int j = 0; j < CHUNK; ++j) {
        o0[j * BLOCK] = acc0[j];
        o1[j * BLOCK] = acc1[j];
    }
}

extern "C" void kernel_launch(void* const* d_in, const int* in_sizes, int n_in,
                              void* d_out, int out_size, void* d_ws, size_t ws_size,
                              hipStream_t stream) {
    const float* log_dt     = (const float*)d_in[0];
    const float* log_a_real = (const float*)d_in[1];
    const float* a_imag     = (const float*)d_in[2];
    const float* coeffs     = (const float*)d_in[3];
    // d_in[4] = sequence_length (== 4096, compile-time constant here)
    float* out = (float*)d_out;

    ssm_vand_kernel<<<dim3(H * HALVES), dim3(BLOCK), 0, stream>>>(
        log_dt, log_a_real, a_imag, coeffs, out);
}

// Round 3
// 93.503 us; speedup vs baseline: 1.0489x; 1.0489x over previous
//
#include <hip/hip_runtime.h>
#include <math.h>

// DiagonalSSMKernel: out[d,h,l] = 2*Re( sum_n scaled_c[d,h,n] * exp(dt[h]*a[h,n]*l) )
// H=1024, N=32 poles, L=4096, 2 dirs. Output fp32 [2,1024,4096] = 33.5 MB.
//
// R3: issue-bound (R2 occupancy-doubling was neutral) -> minimize VALU ops.
//  - grid 1024 (one block per h), CHUNK=16: per-pole setup amortized 2x,
//    and start l = t < 256 so no phase compensation needed.
//  - real 2nd-order resonator recurrence per (pole, dir):
//        x[j+1] = p*x[j] - q*x[j-1],  p = 2*Re(z^256), q = |z^256|^2
//    6 VALU per (pole,j) for both dirs vs 8 for complex-rotate + FMA-acc.

constexpr int H     = 1024;
constexpr int NP    = 32;
constexpr int L     = 4096;
constexpr int BLOCK = 256;
constexpr int CHUNK = 16;   // BLOCK * CHUNK == L

constexpr float  TWOPI    = 6.283185307179586f;
constexpr double INV2PI_D = 0.15915494309189535;

__global__ __launch_bounds__(BLOCK, 4)
void ssm_vand_kernel(const float* __restrict__ log_dt,
                     const float* __restrict__ log_a_real,
                     const float* __restrict__ a_imag,
                     const float* __restrict__ coeffs,
                     float* __restrict__ out)
{
    const int h = blockIdx.x;
    const int t = threadIdx.x;

    // pole[3n+0] = {dar, rate(rev/l), Re(z^256), Im(z^256)}
    // pole[3n+1] = {p=2*Re(z^256), q=|z^256|^2, 2*s0r, 2*s0i}
    // pole[3n+2] = {2*s1r, 2*s1i, 0, 0}
    __shared__ float4 pole[NP * 3];

    if (t < NP) {
        const int n = t;
        const float dtf = expf(log_dt[h]);
        const float ar  = -expf(log_a_real[h * NP + n]);
        const float ai  = a_imag[h * NP + n];
        const float dar = ar * dtf;
        const float dai = ai * dtf;

        // phase rate in revolutions (frac), fp64 once for exactness
        const double rate  = (double)ai * (double)dtf * INV2PI_D;
        const float  rhi   = (float)(rate - floor(rate));

        // z^256
        const float e256 = expf(256.0f * dar);
        double r256 = 256.0 * rate;
        r256 -= floor(r256);
        float s256, c256;
        sincosf((float)r256 * TWOPI, &s256, &c256);
        const float zr = e256 * c256;
        const float zi = e256 * s256;

        // g = (exp(da) - 1) / a
        const float ed = expf(dar);
        float sd, cd;
        sincosf(dai, &sd, &cd);
        const float emr = ed * cd - 1.0f;
        const float emi = ed * sd;
        const float inv = 1.0f / (ar * ar + ai * ai);
        const float gr  = (emr * ar + emi * ai) * inv;
        const float gi  = (emi * ar - emr * ai) * inv;

        const float cr0 = coeffs[((0 * H + h) * NP + n) * 2 + 0];
        const float ci0 = coeffs[((0 * H + h) * NP + n) * 2 + 1];
        const float cr1 = coeffs[((1 * H + h) * NP + n) * 2 + 0];
        const float ci1 = coeffs[((1 * H + h) * NP + n) * 2 + 1];

        pole[n * 3 + 0] = make_float4(dar, rhi, zr, zi);
        pole[n * 3 + 1] = make_float4(2.0f * zr,
                                      zr * zr + zi * zi,
                                      2.0f * (cr0 * gr - ci0 * gi),
                                      2.0f * (cr0 * gi + ci0 * gr));
        pole[n * 3 + 2] = make_float4(2.0f * (cr1 * gr - ci1 * gi),
                                      2.0f * (cr1 * gi + ci1 * gr),
                                      0.0f, 0.0f);
    }
    __syncthreads();

    float acc0[CHUNK];
    float acc1[CHUNK];
    #pragma unroll
    for (int j = 0; j < CHUNK; ++j) { acc0[j] = 0.0f; acc1[j] = 0.0f; }

    const float lf = (float)t;   // start l < 256: no compensation needed

    #pragma unroll 1
    for (int n = 0; n < NP; ++n) {
        const float4 pa = pole[n * 3 + 0];
        const float4 pb = pole[n * 3 + 1];
        const float4 pc = pole[n * 3 + 2];

        // w = exp(da * t) at l = t
        const float m = __expf(pa.x * lf);
        const float ph = pa.y * lf;
        const float rev = ph - floorf(ph);
        float s, c;
        __sincosf(rev * TWOPI, &s, &c);
        const float wr = m * c;
        const float wi = m * s;
        // w2 = w * z^256  (l = t + 256)
        const float wr2 = fmaf(wr, pa.z, -(wi * pa.w));
        const float wi2 = fmaf(wi, pa.z,  (wr * pa.w));

        // real start states per dir (2.0 folded into s)
        float x0p = fmaf(pb.z, wr,  -(pb.w * wi));
        float x0  = fmaf(pb.z, wr2, -(pb.w * wi2));
        float x1p = fmaf(pc.x, wr,  -(pc.y * wi));
        float x1  = fmaf(pc.x, wr2, -(pc.y * wi2));

        acc0[0] += x0p; acc1[0] += x1p;
        acc0[1] += x0;  acc1[1] += x1;

        #pragma unroll
        for (int j = 2; j < CHUNK; ++j) {
            const float n0 = fmaf(pb.x, x0, -(pb.y * x0p));
            const float n1 = fmaf(pb.x, x1, -(pb.y * x1p));
            acc0[j] += n0;
            acc1[j] += n1;
            x0p = x0; x0 = n0;
            x1p = x1; x1 = n1;
        }
    }

    float* o0 = out + (size_t)h * L + t;        // dir 0
    float* o1 = o0 + (size_t)H * L;             // dir 1
    #pragma unroll
    for (int j = 0; j < CHUNK; ++j) {
        o0[j * BLOCK] = acc0[j];
        o1[j * BLOCK] = acc1[j];
    }
}

extern "C" void kernel_launch(void* const* d_in, const int* in_sizes, int n_in,
                              void* d_out, int out_size, void* d_ws, size_t ws_size,
                              hipStream_t stream) {
    const float* log_dt     = (const float*)d_in[0];
    const float* log_a_real = (const float*)d_in[1];
    const float* a_imag     = (const float*)d_in[2];
    const float* coeffs     = (const float*)d_in[3];
    // d_in[4] = sequence_length (== 4096, compile-time constant here)
    float* out = (float*)d_out;

    ssm_vand_kernel<<<dim3(H), dim3(BLOCK), 0, stream>>>(
        log_dt, log_a_real, a_imag, coeffs, out);
}

// Round 4
// 89.546 us; speedup vs baseline: 1.0952x; 1.0442x over previous
//
#include <hip/hip_runtime.h>
#include <math.h>

// DiagonalSSMKernel: out[d,h,l] = 2*Re( sum_n scaled_c[d,h,n] * exp(dt[h]*a[h,n]*l) )
// H=1024, N=32 poles, L=4096, 2 dirs. Output fp32 [2,1024,4096] = 33.5 MB.
//
// R4: issue-bound on VALU -> pack (dir0,dir1) into float2 and let LLVM emit
// VOP3P packed-FP32 (v_pk_fma_f32 / v_pk_mul_f32 / v_pk_add_f32). The two
// directions share recurrence coefficients p,q per pole, so the resonator
//   x[j+1] = p*x[j] - q*x[j-1]
// runs both dirs in one packed op stream: 3 packed inst per (pole,j) vs 6
// scalar. Start states pack identically. Arithmetic is bit-identical to R3.

typedef float v2f __attribute__((ext_vector_type(2)));

constexpr int H     = 1024;
constexpr int NP    = 32;
constexpr int L     = 4096;
constexpr int BLOCK = 256;
constexpr int CHUNK = 16;   // BLOCK * CHUNK == L

constexpr float  TWOPI    = 6.283185307179586f;
constexpr double INV2PI_D = 0.15915494309189535;

__global__ __launch_bounds__(BLOCK, 4)
void ssm_vand_kernel(const float* __restrict__ log_dt,
                     const float* __restrict__ log_a_real,
                     const float* __restrict__ a_imag,
                     const float* __restrict__ coeffs,
                     float* __restrict__ out)
{
    const int h = blockIdx.x;
    const int t = threadIdx.x;

    // pole[3n+0] = {dar, rate(rev/l), Re(z^256), Im(z^256)}
    // pole[3n+1] = {p=2*Re(z^256), q=|z^256|^2, 2*s0r, 2*s0i}
    // pole[3n+2] = {2*s1r, 2*s1i, 0, 0}
    __shared__ float4 pole[NP * 3];

    if (t < NP) {
        const int n = t;
        const float dtf = expf(log_dt[h]);
        const float ar  = -expf(log_a_real[h * NP + n]);
        const float ai  = a_imag[h * NP + n];
        const float dar = ar * dtf;
        const float dai = ai * dtf;

        // phase rate in revolutions (frac), fp64 once for exactness
        const double rate  = (double)ai * (double)dtf * INV2PI_D;
        const float  rhi   = (float)(rate - floor(rate));

        // z^256
        const float e256 = expf(256.0f * dar);
        double r256 = 256.0 * rate;
        r256 -= floor(r256);
        float s256, c256;
        sincosf((float)r256 * TWOPI, &s256, &c256);
        const float zr = e256 * c256;
        const float zi = e256 * s256;

        // g = (exp(da) - 1) / a
        const float ed = expf(dar);
        float sd, cd;
        sincosf(dai, &sd, &cd);
        const float emr = ed * cd - 1.0f;
        const float emi = ed * sd;
        const float inv = 1.0f / (ar * ar + ai * ai);
        const float gr  = (emr * ar + emi * ai) * inv;
        const float gi  = (emi * ar - emr * ai) * inv;

        const float cr0 = coeffs[((0 * H + h) * NP + n) * 2 + 0];
        const float ci0 = coeffs[((0 * H + h) * NP + n) * 2 + 1];
        const float cr1 = coeffs[((1 * H + h) * NP + n) * 2 + 0];
        const float ci1 = coeffs[((1 * H + h) * NP + n) * 2 + 1];

        pole[n * 3 + 0] = make_float4(dar, rhi, zr, zi);
        pole[n * 3 + 1] = make_float4(2.0f * zr,
                                      zr * zr + zi * zi,
                                      2.0f * (cr0 * gr - ci0 * gi),
                                      2.0f * (cr0 * gi + ci0 * gr));
        pole[n * 3 + 2] = make_float4(2.0f * (cr1 * gr - ci1 * gi),
                                      2.0f * (cr1 * gi + ci1 * gr),
                                      0.0f, 0.0f);
    }
    __syncthreads();

    v2f acc[CHUNK];
    #pragma unroll
    for (int j = 0; j < CHUNK; ++j) acc[j] = (v2f){0.0f, 0.0f};

    const float lf = (float)t;   // start l < 256: no compensation needed

    #pragma unroll 1
    for (int n = 0; n < NP; ++n) {
        const float4 pa = pole[n * 3 + 0];
        const float4 pb = pole[n * 3 + 1];
        const float4 pc = pole[n * 3 + 2];

        // w = exp(da * t) at l = t   (shared across dirs)
        const float m = __expf(pa.x * lf);
        const float ph = pa.y * lf;
        const float rev = ph - floorf(ph);
        float s, c;
        __sincosf(rev * TWOPI, &s, &c);
        const float wr = m * c;
        const float wi = m * s;
        // w2 = w * z^256  (l = t + 256)
        const float wr2 = fmaf(wr, pa.z, -(wi * pa.w));
        const float wi2 = fmaf(wi, pa.z,  (wr * pa.w));

        // packed start states: lane = (dir0, dir1)
        const v2f sr = {pb.z, pc.x};
        const v2f si = {pb.w, pc.y};
        const v2f p  = {pb.x, pb.x};
        const v2f q  = {pb.y, pb.y};

        v2f xp = __builtin_elementwise_fma(sr, (v2f){wr,  wr},  -(si * (v2f){wi,  wi}));
        v2f x  = __builtin_elementwise_fma(sr, (v2f){wr2, wr2}, -(si * (v2f){wi2, wi2}));

        acc[0] += xp;
        acc[1] += x;

        #pragma unroll
        for (int j = 2; j < CHUNK; ++j) {
            const v2f nx = __builtin_elementwise_fma(p, x, -(q * xp));
            acc[j] += nx;
            xp = x;
            x  = nx;
        }
    }

    float* o0 = out + (size_t)h * L + t;        // dir 0
    float* o1 = o0 + (size_t)H * L;             // dir 1
    #pragma unroll
    for (int j = 0; j < CHUNK; ++j) {
        o0[j * BLOCK] = acc[j].x;
        o1[j * BLOCK] = acc[j].y;
    }
}

extern "C" void kernel_launch(void* const* d_in, const int* in_sizes, int n_in,
                              void* d_out, int out_size, void* d_ws, size_t ws_size,
                              hipStream_t stream) {
    const float* log_dt     = (const float*)d_in[0];
    const float* log_a_real = (const float*)d_in[1];
    const float* a_imag     = (const float*)d_in[2];
    const float* coeffs     = (const float*)d_in[3];
    // d_in[4] = sequence_length (== 4096, compile-time constant here)
    float* out = (float*)d_out;

    ssm_vand_kernel<<<dim3(H), dim3(BLOCK), 0, stream>>>(
        log_dt, log_a_real, a_imag, coeffs, out);
}